// Round 3
// baseline (246.801 us; speedup 1.0000x reference)
//
#include <hip/hip_runtime.h>
#include <stdint.h>

constexpr int K      = 49;           // 7x7 kernel flattened
constexpr int C      = 32;           // out channels
constexpr int BLK    = 256;          // 4 waves/block
constexpr int TILE   = 64;           // windows per tile
constexpr int TILE_F = TILE * K;     // 3136 floats = 12544 B
constexpr int GRID   = 1536;         // 6 blocks/CU x 256 CU, all co-resident
constexpr int CPW    = C / 4;        // 8 channels per wave

#define GPTR(p) ((const __attribute__((address_space(1))) uint32_t*)(p))
#define LPTR(p) ((__attribute__((address_space(3))) uint32_t*)(p))

// Stage one 12544 B tile global->LDS: 3 width-16 rounds (all 256 threads)
// + 1 masked width-4 round (lanes 0..15 of each wave) = 4 vmcnt ops per wave.
__device__ __forceinline__ void prefetch_tile(const float* __restrict__ g,
                                              float* buf, int t) {
#pragma unroll
    for (int r = 0; r < 3; ++r)
        __builtin_amdgcn_global_load_lds(GPTR(g + r * 1024 + t * 4),
                                         LPTR(buf + r * 1024 + t * 4), 16, 0, 0);
    const int lane = t & 63, wid = t >> 6;          // remainder: 64 floats
    if (lane < 16)
        __builtin_amdgcn_global_load_lds(GPTR(g + 3072 + wid * 16 + lane),
                                         LPTR(buf + 3072 + wid * 16 + lane), 4, 0, 0);
}

__global__ __launch_bounds__(BLK, 6) void conv2d_im2col_hiocc(
    const float* __restrict__ enc_x,
    const float* __restrict__ weight,   // [C*K] wave-uniform -> s_load
    const float* __restrict__ bias,     // [C]
    float* __restrict__ out,            // [C * windows_nb]
    int windows_nb)
{
    __shared__ __align__(16) float bufA[TILE_F];    // 12544 B
    __shared__ __align__(16) float bufB[TILE_F];    // 12544 B -> 25088 B/block

    const int t    = threadIdx.x;
    const int lane = t & 63;
    const int wid  = t >> 6;            // wave id 0..3 -> channel group
    const int c0   = wid * CPW;         // this wave's first channel
    const int b    = blockIdx.x;

    const int ntiles = windows_nb / TILE;               // 16384
    const int nt     = (ntiles - b + GRID - 1) / GRID;  // 10 or 11

    // Prologue: fill both buffers (tiles 0 and 1). 4 vmcnt ops each.
    prefetch_tile(enc_x + (size_t)b * TILE_F, bufA, t);
    if (nt > 1)
        prefetch_tile(enc_x + (size_t)(b + GRID) * TILE_F, bufB, t);

    const float* __restrict__ wp = weight + c0 * K;     // uniform per wave

    // Per-wave VMEM FIFO per iteration j:
    //   ... loads_j(4) | stores_{j-1}(8) | loads_{j+1}(4) | [wait here] ...
    //   allowed outstanding at wait = (j>0 ? 8 : 0) + (j+1<nt ? 4 : 0)
    auto body = [&](float* buf, int j) {
        const long tile = b + (long)j * GRID;

        if (j == 0) {
            if (nt > 1) asm volatile("s_waitcnt vmcnt(4)" ::: "memory");
            else        asm volatile("s_waitcnt vmcnt(0)" ::: "memory");
        } else if (j + 1 < nt) {
            asm volatile("s_waitcnt vmcnt(12)" ::: "memory");
        } else {
            asm volatile("s_waitcnt vmcnt(8)" ::: "memory");
        }
        __builtin_amdgcn_s_barrier();            // tile j fully staged
        asm volatile("" ::: "memory");

        // Each lane owns window (tile*64+lane); wave owns channels c0..c0+7.
        // LDS pattern lane*49+k: gcd(49,32)=1 -> 2 lanes/bank (free).
        const float* __restrict__ xrow = buf + lane * K;
        float acc[CPW];
#pragma unroll
        for (int cc = 0; cc < CPW; ++cc) acc[cc] = bias[c0 + cc];

        for (int k = 0; k < K; ++k) {
            const float xv = xrow[k];
#pragma unroll
            for (int cc = 0; cc < CPW; ++cc)
                acc[cc] = fmaf(xv, wp[cc * K + k], acc[cc]);
        }

        const size_t w = (size_t)tile * TILE + lane;
#pragma unroll
        for (int cc = 0; cc < CPW; ++cc)
            out[(size_t)(c0 + cc) * windows_nb + w] = acc[cc];

        asm volatile("" ::: "memory");
        __builtin_amdgcn_s_barrier();            // buf free for overwrite
        asm volatile("" ::: "memory");

        if (j + 2 < nt)                          // refill the buffer just used
            prefetch_tile(enc_x + (size_t)(tile + 2 * GRID) * TILE_F, buf, t);
    };

    // 2x unrolled: compile-time buffer pointers (no runtime LDS select).
    int j = 0;
    for (; j + 1 < nt; j += 2) {
        body(bufA, j);
        body(bufB, j + 1);
    }
    if (j < nt) body(bufA, j);
}

extern "C" void kernel_launch(void* const* d_in, const int* in_sizes, int n_in,
                              void* d_out, int out_size, void* d_ws, size_t ws_size,
                              hipStream_t stream) {
    const float* enc_x  = (const float*)d_in[0];
    const float* weight = (const float*)d_in[1];   // [C,7,7] flat
    const float* bias   = (const float*)d_in[2];   // [C]
    float* out = (float*)d_out;

    const int windows_nb = in_sizes[0] / K;        // 1048576

    conv2d_im2col_hiocc<<<GRID, BLK, 0, stream>>>(enc_x, weight, bias, out, windows_nb);
}

// Round 4
// 84.920 us; speedup vs baseline: 2.9063x; 2.9063x over previous
//
#include <hip/hip_runtime.h>
#include <stdint.h>

constexpr int K      = 49;           // 7x7 kernel flattened
constexpr int C      = 32;           // out channels
constexpr int TILE   = 64;           // windows per block = lanes per wave
constexpr int TILE_F = TILE * K;     // 3136 floats = 12544 B

#define GPTR(p) ((const __attribute__((address_space(1))) uint32_t*)(p))
#define LPTR(p) ((__attribute__((address_space(3))) uint32_t*)(p))

// One wave per block. 12.5 KB LDS -> 12 independent blocks/CU, no barriers,
// scheduler-staggered phases hide each wave's vmcnt(0) drain.
__global__ __launch_bounds__(TILE) void conv2d_tile64(
    const float* __restrict__ enc_x,
    const float* __restrict__ weight,   // [C*K]; c-outer/k-unrolled -> s_load_dwordx16
    const float* __restrict__ bias,     // [C]
    float* __restrict__ out,            // [C * windows_nb]
    int windows_nb)
{
    __shared__ __align__(16) float xs[TILE_F];   // 12544 B

    const int lane = threadIdx.x;
    const size_t b = blockIdx.x;
    const float* __restrict__ g = enc_x + b * TILE_F;

    // Stage 12544 B global->LDS: 12 x (64 lanes x 16B) + 1 x (64 lanes x 4B).
    // Fully coalesced, zero VGPR round-trip, zero over-fetch.
#pragma unroll
    for (int r = 0; r < 12; ++r)
        __builtin_amdgcn_global_load_lds(GPTR(g + r * 256 + lane * 4),
                                         LPTR(xs + r * 256 + lane * 4), 16, 0, 0);
    __builtin_amdgcn_global_load_lds(GPTR(g + 3072 + lane),
                                     LPTR(xs + 3072 + lane), 4, 0, 0);

    asm volatile("s_waitcnt vmcnt(0)" ::: "memory");   // tile staged (1-wave block: no barrier)

    // Window row -> registers. Stride 49 (odd) -> 2 lanes/bank -> conflict-free.
    float x[K];
#pragma unroll
    for (int k = 0; k < K; ++k) x[k] = xs[lane * K + k];

    const size_t w = b * TILE + lane;

    // c outer, k fully unrolled: wc[0..48] consecutive -> 3x s_load_dwordx16 + 1.
    // unroll 2 so next channel's scalar weight loads pipeline under current FMAs.
#pragma unroll 2
    for (int c = 0; c < C; ++c) {
        const float* __restrict__ wc = weight + c * K;
        float a0 = bias[c], a1 = 0.f, a2 = 0.f, a3 = 0.f;
#pragma unroll
        for (int k = 0; k < K; k += 4) {
            a0 = fmaf(x[k], wc[k], a0);
            if (k + 1 < K) a1 = fmaf(x[k + 1], wc[k + 1], a1);
            if (k + 2 < K) a2 = fmaf(x[k + 2], wc[k + 2], a2);
            if (k + 3 < K) a3 = fmaf(x[k + 3], wc[k + 3], a3);
        }
        out[(size_t)c * windows_nb + w] = (a0 + a1) + (a2 + a3);
    }
}

extern "C" void kernel_launch(void* const* d_in, const int* in_sizes, int n_in,
                              void* d_out, int out_size, void* d_ws, size_t ws_size,
                              hipStream_t stream) {
    const float* enc_x  = (const float*)d_in[0];
    const float* weight = (const float*)d_in[1];   // [C,7,7] flat
    const float* bias   = (const float*)d_in[2];   // [C]
    float* out = (float*)d_out;

    const int windows_nb = in_sizes[0] / K;        // 1048576
    const int nblocks = windows_nb / TILE;         // 16384

    conv2d_tile64<<<nblocks, TILE, 0, stream>>>(enc_x, weight, bias, out, windows_nb);
}